// Round 13
// baseline (4124.689 us; speedup 1.0000x reference)
//
#include <hip/hip_runtime.h>

#define Bb 256
#define Ll 1024
#define Ff 64
#define Ee 128
#define Hh 128
#define CH 32

typedef _Float16 h2v __attribute__((ext_vector_type(2)));

__device__ __forceinline__ unsigned pack_h2(float a, float b) {
  h2v v; v[0] = (_Float16)a; v[1] = (_Float16)b;
  return __builtin_bit_cast(unsigned, v);
}
__device__ __forceinline__ float dot2(unsigned w, unsigned x, float acc) {
#if defined(__has_builtin) && __has_builtin(__builtin_amdgcn_fdot2)
  return __builtin_amdgcn_fdot2(__builtin_bit_cast(h2v, w),
                                __builtin_bit_cast(h2v, x), acc, false);
#else
  h2v wv = __builtin_bit_cast(h2v, w), xv = __builtin_bit_cast(h2v, x);
  acc = fmaf((float)wv[0], (float)xv[0], acc);
  return fmaf((float)wv[1], (float)xv[1], acc);
#endif
}
__device__ __forceinline__ float dppadd1(float v) {   // + lane^1 (quad_perm)
  int s = __builtin_amdgcn_mov_dpp(__builtin_bit_cast(int, v), 0xB1, 0xF, 0xF, true);
  return v + __builtin_bit_cast(float, s);
}
__device__ __forceinline__ float dppadd2(float v) {   // + lane^2 (quad_perm)
  int s = __builtin_amdgcn_mov_dpp(__builtin_bit_cast(int, v), 0x4E, 0xF, 0xF, true);
  return v + __builtin_bit_cast(float, s);
}
// full sum across the 8 K-slice lanes (bits 0..2): 2 DPP hops + xor-4
__device__ __forceinline__ float qsum8(float a0, float a1) {
  float v = dppadd2(dppadd1(a0 + a1));
  return v + __shfl_xor(v, 4);
}
__device__ __forceinline__ float fast_tanh(float x) {
  float e = __expf(2.0f * x);
  return 1.0f - 2.0f / (e + 1.0f);
}
__device__ __forceinline__ float fast_sigmoid(float x) {
  return 1.0f / (1.0f + __expf(-x));
}

// 16-wide K-slice matvec: 8 dot2, 2 chains, 8-lane reduce
__device__ __forceinline__ float mv8(const unsigned* __restrict__ w,
                                     const unsigned* __restrict__ v, int q0) {
  const uint4 h0 = *(const uint4*)&v[q0];
  const uint4 h1 = *(const uint4*)&v[q0 + 4];
  float a0 = 0.0f, a1 = 0.0f;
  a0 = dot2(w[0], h0.x, a0); a1 = dot2(w[1], h0.y, a1);
  a0 = dot2(w[2], h0.z, a0); a1 = dot2(w[3], h0.w, a1);
  a0 = dot2(w[4], h1.x, a0); a1 = dot2(w[5], h1.y, a1);
  a0 = dot2(w[6], h1.z, a0); a1 = dot2(w[7], h1.w, a1);
  return qsum8(a0, a1);
}
// gi gate from LDS-resident (XOR-swizzled) Wih row
__device__ __forceinline__ float gi8(const unsigned* __restrict__ wrow,
                                     const unsigned* __restrict__ xe,
                                     int q0, int swi) {
  const uint4 x0 = *(const uint4*)&xe[q0];
  const uint4 x1 = *(const uint4*)&xe[q0 + 4];
  const uint4 w0 = *(const uint4*)&wrow[q0 ^ swi];
  const uint4 w1 = *(const uint4*)&wrow[(q0 + 4) ^ swi];
  float g0 = 0.0f, g1 = 0.0f;
  g0 = dot2(w0.x, x0.x, g0); g1 = dot2(w0.y, x0.y, g1);
  g0 = dot2(w0.z, x0.z, g0); g1 = dot2(w0.w, x0.w, g1);
  g0 = dot2(w1.x, x1.x, g0); g1 = dot2(w1.y, x1.y, g1);
  g0 = dot2(w1.z, x1.z, g0); g1 = dot2(w1.w, x1.w, g1);
  return qsum8(g0, g1);
}

// One WG (1024 thr, 16 waves = 4 waves/SIMD) per batch row.
// j = wv*8 + (lane>>3), ks = lane&7 (16-wide K-slice).
__global__ __launch_bounds__(1024, 1) void k_fused(
    const float* __restrict__ x, const float* __restrict__ dtp,
    const int* __restrict__ mask,
    const float* __restrict__ Wx, const float* __restrict__ bx,
    const float* __restrict__ W1, const float* __restrict__ b1,
    const float* __restrict__ W2, const float* __restrict__ b2,
    const float* __restrict__ Wih, const float* __restrict__ bih,
    const float* __restrict__ Whh, const float* __restrict__ bhh,
    const float* __restrict__ lng, const float* __restrict__ lnb,
    const float* __restrict__ Whd, const float* __restrict__ bhp,
    float* __restrict__ out)
{
  const int b = blockIdx.x;
  const int tid = threadIdx.x;
  const int lane = tid & 63;
  const int wv = tid >> 6;            // 0..15
  const int jq = lane >> 3;           // 0..7
  const int ks = lane & 7;            // 0..7
  const int j = (wv << 3) + jq;       // 0..127
  const int q0 = ks << 3;             // u32 base in 64-u32 (K=128) arrays
  const int q0x = ks << 2;            // u32 base in 32-u32 (F=64) rows
  const int swi = (j & 15) << 2;
  const int swx = (j & 7) << 2;

  __shared__ int act_lds[Ll];                               // 4 KB
  __shared__ __align__(16) unsigned wih_lds[3 * Hh * 64];   // 96 KB, swizzled
  __shared__ __align__(16) unsigned wx_lds[Hh * 32];        // 16 KB, swizzled
  __shared__ __align__(16) unsigned x16[CH * 32];           // 4 KB
  __shared__ __align__(16) unsigned xe16[Ee / 2];
  __shared__ __align__(16) unsigned u16[Hh / 2];
  __shared__ __align__(16) unsigned h16[2][Hh / 2];
  __shared__ float bias_lds[6 * Hh];
  __shared__ float dt_ch[CH];
  __shared__ int   m_ch[CH];
  __shared__ float red_lds[96];                             // 3 × 32 slots
  __shared__ float accbuf[16], cntbuf[16];
  __shared__ float cc_lds[2];

  // ---- act prepass (lane-consecutive t: coalesced) ----
  for (int t0 = tid; t0 < Ll; t0 += 1024) {
    int a = 0;
#pragma unroll 8
    for (int bb = 0; bb < Bb; ++bb) a |= mask[(size_t)bb * Ll + t0];
    act_lds[t0] = a;
  }
  // ---- Wih -> LDS f16 pairs, XOR-swizzled per 64-word row ----
  for (int idx = tid; idx < 3 * Hh * 64; idx += 1024) {
    const int r = idx >> 6, w = idx & 63;
    wih_lds[(r << 6) | (w ^ ((r & 15) << 2))] =
        pack_h2(Wih[(size_t)r * Ee + 2 * w], Wih[(size_t)r * Ee + 2 * w + 1]);
  }
  // ---- Wx -> LDS f16 pairs, XOR-swizzled per 32-word row ----
  for (int idx = tid; idx < Hh * 32; idx += 1024) {
    const int r = idx >> 5, w = idx & 31;
    wx_lds[(r << 5) | (w ^ ((r & 7) << 2))] =
        pack_h2(Wx[(size_t)r * Ff + 2 * w], Wx[(size_t)r * Ff + 2 * w + 1]);
  }
  // ---- per-j biases -> LDS ----
  for (int i = tid; i < 3 * Hh; i += 1024) {
    bias_lds[i] = bih[i];
    bias_lds[3 * Hh + i] = bhh[i];
  }
  if (tid == 0) {
    float s1 = 0.0f, s0 = 0.0f;
    for (int i = 0; i < Hh; ++i) { s1 += lng[i] * Whd[i]; s0 += lnb[i] * Whd[i]; }
    cc_lds[0] = s1; cc_lds[1] = s0 + bhp[0];
  }
  // ---- register-stationary weights (f16 pairs, 40 u32) ----
  unsigned w1h[8], w2h[8], whr[8], whz[8], whn[8];
#pragma unroll
  for (int ii = 0; ii < 4; ++ii) {
    float4 a4;
    a4 = *(const float4*)&W1[(size_t)j * Hh + (ks << 4) + 4 * ii];
    w1h[2*ii] = pack_h2(a4.x, a4.y); w1h[2*ii+1] = pack_h2(a4.z, a4.w);
    a4 = *(const float4*)&W2[(size_t)j * Hh + (ks << 4) + 4 * ii];
    w2h[2*ii] = pack_h2(a4.x, a4.y); w2h[2*ii+1] = pack_h2(a4.z, a4.w);
    a4 = *(const float4*)&Whh[(size_t)j * Hh + (ks << 4) + 4 * ii];
    whr[2*ii] = pack_h2(a4.x, a4.y); whr[2*ii+1] = pack_h2(a4.z, a4.w);
    a4 = *(const float4*)&Whh[(size_t)(Hh + j) * Hh + (ks << 4) + 4 * ii];
    whz[2*ii] = pack_h2(a4.x, a4.y); whz[2*ii+1] = pack_h2(a4.z, a4.w);
    a4 = *(const float4*)&Whh[(size_t)(2 * Hh + j) * Hh + (ks << 4) + 4 * ii];
    whn[2*ii] = pack_h2(a4.x, a4.y); whn[2*ii+1] = pack_h2(a4.z, a4.w);
  }
  const float bxj = bx[j];
  const float b1j = b1[j], b2j = b2[j];
  const float gw = lng[j] * Whd[j];

  if (tid < Hh) ((unsigned*)h16)[tid] = 0u;   // zero both buffers
  float hreg = 0.0f, gir = 0.0f, giz = 0.0f, gin = 0.0f;
  float accw = 0.0f, cntw = 0.0f;             // per-wave logit accumulator
  int pp = 0;
  __syncthreads();

#pragma unroll 1
  for (int t = 0; t < Ll; ++t) {
    const int tc = t & (CH - 1);
    if (tc == 0) {
      // ---- chunk refill: 32 steps of x (f16-packed) + dt + mask ----
      const int st = tid >> 5, g = tid & 31;
      const float2 a = *(const float2*)(x + ((size_t)b * Ll + t + st) * Ff + g * 2);
      x16[st * 32 + g] = pack_h2(a.x, a.y);
      if (tid < CH) dt_ch[tid] = dtp[(size_t)b * Ll + t + tid];
      else if (tid < 2 * CH) m_ch[tid - CH] = mask[(size_t)b * Ll + t + (tid - CH)];
      __syncthreads();
    }
    const float dtv = dt_ch[tc];
    const int m = m_ch[tc];
    const int act = act_lds[t];
    const float stepv = dtv * (float)m * 0.25f;
    unsigned* hcur = h16[pp];

    // ---- phase A: xe + ODE substep0 matvec1 ----
    {
      const uint4 xv = *(const uint4*)&x16[tc * 32 + q0x];
      const uint4 w4 = *(const uint4*)&wx_lds[(j << 5) + (q0x ^ swx)];
      float p0 = 0.0f, p1 = 0.0f;
      p0 = dot2(w4.x, xv.x, p0); p1 = dot2(w4.y, xv.y, p1);
      p0 = dot2(w4.z, xv.z, p0); p1 = dot2(w4.w, xv.w, p1);
      const float xev = fmaxf(qsum8(p0, p1) + bxj, 0.0f);
      if (ks == 0) ((_Float16*)xe16)[j] = (_Float16)xev;

      const float uu = fast_tanh(mv8(w1h, hcur, q0) + b1j);
      if (ks == 0) ((_Float16*)u16)[j] = (_Float16)uu;
    }
    __syncthreads();                         // C0

    // ---- phase B: substep0 matvec2 + gi_r ----
    {
      hreg = fmaf(stepv, mv8(w2h, u16, q0) + b2j, hreg);
      if (ks == 0) ((_Float16*)hcur)[j] = (_Float16)hreg;
      gir = gi8(&wih_lds[j << 6], xe16, q0, swi) + bias_lds[j];
    }
    __syncthreads();                         // D0

    // ---- substep1 + gi_z / gi_n ----
    {
      const float uu = fast_tanh(mv8(w1h, hcur, q0) + b1j);
      if (ks == 0) ((_Float16*)u16)[j] = (_Float16)uu;
      giz = gi8(&wih_lds[(Hh + j) << 6], xe16, q0, swi) + bias_lds[Hh + j];
    }
    __syncthreads();                         // C1
    {
      hreg = fmaf(stepv, mv8(w2h, u16, q0) + b2j, hreg);
      if (ks == 0) ((_Float16*)hcur)[j] = (_Float16)hreg;
      gin = gi8(&wih_lds[(2 * Hh + j) << 6], xe16, q0, swi) + bias_lds[2 * Hh + j];
    }
    __syncthreads();                         // D1

    // ---- substeps 2,3 ----
#pragma unroll
    for (int s = 2; s < 4; ++s) {
      {
        const float uu = fast_tanh(mv8(w1h, hcur, q0) + b1j);
        if (ks == 0) ((_Float16*)u16)[j] = (_Float16)uu;
      }
      __syncthreads();                       // C_s
      {
        hreg = fmaf(stepv, mv8(w2h, u16, q0) + b2j, hreg);
        if (ks == 0) ((_Float16*)hcur)[j] = (_Float16)hreg;
      }
      __syncthreads();                       // D_s
    }

    // ---- phase G: GRU + LN partials ----
    {
      const uint4 h0 = *(const uint4*)&hcur[q0];
      const uint4 h1 = *(const uint4*)&hcur[q0 + 4];
      float pr = 0.0f, pz = 0.0f, pn = 0.0f;
      pr = dot2(whr[0], h0.x, pr); pr = dot2(whr[1], h0.y, pr);
      pr = dot2(whr[2], h0.z, pr); pr = dot2(whr[3], h0.w, pr);
      pr = dot2(whr[4], h1.x, pr); pr = dot2(whr[5], h1.y, pr);
      pr = dot2(whr[6], h1.z, pr); pr = dot2(whr[7], h1.w, pr);
      pz = dot2(whz[0], h0.x, pz); pz = dot2(whz[1], h0.y, pz);
      pz = dot2(whz[2], h0.z, pz); pz = dot2(whz[3], h0.w, pz);
      pz = dot2(whz[4], h1.x, pz); pz = dot2(whz[5], h1.y, pz);
      pz = dot2(whz[6], h1.z, pz); pz = dot2(whz[7], h1.w, pz);
      pn = dot2(whn[0], h0.x, pn); pn = dot2(whn[1], h0.y, pn);
      pn = dot2(whn[2], h0.z, pn); pn = dot2(whn[3], h0.w, pn);
      pn = dot2(whn[4], h1.x, pn); pn = dot2(whn[5], h1.y, pn);
      pn = dot2(whn[6], h1.z, pn); pn = dot2(whn[7], h1.w, pn);
      pr = qsum8(pr, 0.0f) + bias_lds[3 * Hh + j];
      pz = qsum8(pz, 0.0f) + bias_lds[4 * Hh + j];
      pn = qsum8(pn, 0.0f) + bias_lds[5 * Hh + j];
      const float r = fast_sigmoid(gir + pr);
      const float z = fast_sigmoid(giz + pz);
      const float n = fast_tanh(gin + r * pn);
      const float hg = (1.0f - z) * n + z * hreg;
      if (act) hreg = hg;
      if (ks == 0) ((_Float16*)h16[pp ^ 1])[j] = (_Float16)hreg;

      // LN partials over the wave's 8 j's: xor-8, xor-16; 2 writer lanes
      float s1 = hreg, s2 = hreg * hreg, sd = hreg * gw;
      s1 += __shfl_xor(s1, 8);  s2 += __shfl_xor(s2, 8);  sd += __shfl_xor(sd, 8);
      s1 += __shfl_xor(s1, 16); s2 += __shfl_xor(s2, 16); sd += __shfl_xor(sd, 16);
      if ((lane & 31) == 0) {
        const int slot = (wv << 1) | (lane >> 5);
        red_lds[slot] = s1; red_lds[32 + slot] = s2; red_lds[64 + slot] = sd;
      }
    }
    __syncthreads();                         // E

    // ---- rotating finalizer wave ----
    if (wv == (t & 15) && m) {
      float v1 = 0.0f, v2 = 0.0f, v3 = 0.0f;
      if (lane < 32) { v1 = red_lds[lane]; v2 = red_lds[32 + lane]; v3 = red_lds[64 + lane]; }
#pragma unroll
      for (int o = 1; o <= 16; o <<= 1) {
        v1 += __shfl_xor(v1, o); v2 += __shfl_xor(v2, o); v3 += __shfl_xor(v3, o);
      }
      const float mu = v1 * (1.0f / 128.0f);
      const float var = v2 * (1.0f / 128.0f) - mu * mu;
      const float rstd = rsqrtf(var + 1e-5f);
      accw += rstd * (v3 - mu * cc_lds[0]) + cc_lds[1];
      cntw += 1.0f;
    }
    pp ^= 1;
  }

  if (lane == 0) { accbuf[wv] = accw; cntbuf[wv] = cntw; }
  __syncthreads();
  if (tid == 0) {
    float a = 0.0f, c = 0.0f;
#pragma unroll
    for (int q = 0; q < 16; ++q) { a += accbuf[q]; c += cntbuf[q]; }
    out[b] = a / fmaxf(c, 1.0f);             // FLOAT32 output
  }
}

// ---------------- host ----------------
extern "C" void kernel_launch(void* const* d_in, const int* in_sizes, int n_in,
                              void* d_out, int out_size, void* d_ws, size_t ws_size,
                              hipStream_t stream) {
  const float* x    = (const float*)d_in[0];
  const float* dt   = (const float*)d_in[1];
  const int*   mask = (const int*)d_in[2];
  const float* Wx   = (const float*)d_in[3];
  const float* bx   = (const float*)d_in[4];
  const float* W1   = (const float*)d_in[5];
  const float* b1   = (const float*)d_in[6];
  const float* W2   = (const float*)d_in[7];
  const float* b2   = (const float*)d_in[8];
  const float* Wih  = (const float*)d_in[9];
  const float* bih  = (const float*)d_in[10];
  const float* Whh  = (const float*)d_in[11];
  const float* bhh  = (const float*)d_in[12];
  const float* lng  = (const float*)d_in[13];
  const float* lnb  = (const float*)d_in[14];
  const float* Wh   = (const float*)d_in[15];
  const float* bh   = (const float*)d_in[16];
  float* out = (float*)d_out;

  k_fused<<<dim3(Bb), dim3(1024), 0, stream>>>(
      x, dt, mask, Wx, bx, W1, b1, W2, b2, Wih, bih, Whh, bhh,
      lng, lnb, Wh, bh, out);
}